// Round 1
// 256.568 us; speedup vs baseline: 1.0011x; 1.0011x over previous
//
#include <hip/hip_runtime.h>
#include <hip/hip_bf16.h>
#include <stdint.h>

constexpr int BB  = 64;    // batch
constexpr int SS  = 512;   // seq len
constexpr int HH  = 768;   // hidden
constexpr int NL  = 9;     // labels
constexpr int NROWS = BB * SS;          // 32768
constexpr int EMN   = SS * NL;          // 4608 emissions per batch
constexpr int NSEG  = 8;                // time segments for parallel lognorm
constexpr float NEG  = -1e30f;

__device__ __forceinline__ float readlane_f(float v, int lane) {
  union { float f; int i; } u;
  u.f = v;
  u.i = __builtin_amdgcn_readlane(u.i, lane);
  return u.f;
}

// ---------------------------------------------------------------------------
// Kernel 1: logits[b,s,l] = hidden[b,s,:] @ W[:,l] + bias[l]
// One wave per 4 rows, all 4 in flight (butterfly chains interleave).
// Blocks 0..63 additionally compute lens[b]. Block 0 zeroes the loss acc
// (replaces the hipMemsetAsync graph node).
// ---------------------------------------------------------------------------
__global__ __launch_bounds__(256, 2) void logits_kernel(
    const float* __restrict__ hidden, const float* __restrict__ W,
    const float* __restrict__ bias, const int* __restrict__ mask,
    float* __restrict__ logits, int* __restrict__ lens,
    float* __restrict__ out) {
  const int lane = threadIdx.x & 63;
  const int wid  = blockIdx.x * 4 + (threadIdx.x >> 6);   // 8192 waves

  if (blockIdx.x == 0 && threadIdx.x == 0) out[0] = 0.0f;

  if (blockIdx.x < 64 && threadIdx.x < 64) {
    const int4* mp = (const int4*)(mask + blockIdx.x * SS);
    const int4 a = mp[threadIdx.x];
    const int4 c = mp[threadIdx.x + 64];
    int lsum = a.x + a.y + a.z + a.w + c.x + c.y + c.z + c.w;
#pragma unroll
    for (int off = 32; off >= 1; off >>= 1) lsum += __shfl_xor(lsum, off, 64);
    if (threadIdx.x == 0) lens[blockIdx.x] = lsum;
  }

  float w[3][4][NL];
#pragma unroll
  for (int j = 0; j < 3; ++j)
#pragma unroll
    for (int k = 0; k < 4; ++k) {
      const int r = lane * 4 + j * 256 + k;
#pragma unroll
      for (int l = 0; l < NL; ++l) w[j][k][l] = W[r * NL + l];
    }
  const float my_bias = (lane < NL) ? bias[lane] : 0.0f;

  // 4 rows in flight
  float4 h[4][3];
#pragma unroll
  for (int r = 0; r < 4; ++r) {
    const float4* hp = (const float4*)(hidden + (size_t)(wid + r * 8192) * HH);
#pragma unroll
    for (int j = 0; j < 3; ++j) h[r][j] = hp[lane + j * 64];
  }
  float acc[4][NL];
#pragma unroll
  for (int r = 0; r < 4; ++r)
#pragma unroll
    for (int l = 0; l < NL; ++l) acc[r][l] = 0.0f;
#pragma unroll
  for (int r = 0; r < 4; ++r)
#pragma unroll
    for (int j = 0; j < 3; ++j)
#pragma unroll
      for (int l = 0; l < NL; ++l)
        acc[r][l] += h[r][j].x * w[j][0][l] + h[r][j].y * w[j][1][l] +
                     h[r][j].z * w[j][2][l] + h[r][j].w * w[j][3][l];
#pragma unroll
  for (int off = 32; off >= 1; off >>= 1)
#pragma unroll
    for (int r = 0; r < 4; ++r)
#pragma unroll
      for (int l = 0; l < NL; ++l)
        acc[r][l] += __shfl_xor(acc[r][l], off, 64);
  if (lane < NL) {
#pragma unroll
    for (int r = 0; r < 4; ++r) {
      float v = acc[r][0];
#pragma unroll
      for (int l = 1; l < NL; ++l) if (lane == l) v = acc[r][l];
      logits[(size_t)(wid + r * 8192) * NL + lane] = v + my_bias;
    }
  }
}

// ---------------------------------------------------------------------------
// Kernel 2: scan kernel, 1664 one-wave blocks.
//   blk   0..  63 : viterbi (bit-exact ref arithmetic) + backtrace
//                   emissions LDS-staged (cross-XCD L2 misses were the stall),
//                   fused max/argmax tree, s_setprio(1) on the serial chain.
//   blk  64.. 127 : numerator (gold-path score), parallel over t
//   blk 128..1663 : lognorm segment scans, 3 basis chains per wave (ILP-3)
// ---------------------------------------------------------------------------
__global__ __launch_bounds__(64) void scan_kernel(
    const float* __restrict__ logits, const int* __restrict__ labels,
    const float* __restrict__ start_t, const float* __restrict__ end_t,
    const float* __restrict__ trans, float* __restrict__ out,
    float* __restrict__ num_den, const int* __restrict__ lens,
    float* __restrict__ segmat) {
  __shared__ float4 embv[1161];                 // 4644 floats (pad covers t+4 prefetch)
  __shared__ unsigned char bp_s[EMN + 80];
  __shared__ unsigned char tags_s[SS];
  __shared__ unsigned char lab[SS];

  const int blk = blockIdx.x;
  const int tid = threadIdx.x;
  const int j   = (tid < NL) ? tid : NL - 1;

  if (blk < 64) {
    // ================= viterbi =================
    __builtin_amdgcn_s_setprio(1);              // critical serial chain: win arbitration
    const int b   = blk;
    const int len = lens[b];
    const float* emb = logits + (size_t)b * EMN;

    // stage this batch's emissions into LDS (one coalesced burst; per-step
    // reads were L3-latency-bound: logits written by other XCDs' CUs)
    {
      const float4* src = (const float4*)emb;
#pragma unroll
      for (int i = 0; i < 18; ++i) embv[tid + i * 64] = src[tid + i * 64];
    }
    __syncthreads();
    const float* emb_s = (const float*)embv;

    float tc[NL];
#pragma unroll
    for (int i = 0; i < NL; ++i) tc[i] = trans[i * NL + j];
    float s[NL];
#pragma unroll
    for (int i = 0; i < NL; ++i) s[i] = start_t[i] + emb_s[i];
    float eA = emb_s[1 * NL + j], eB = emb_s[2 * NL + j];
    float eC = emb_s[3 * NL + j], eD = emb_s[4 * NL + j];
    for (int t = 1; t < len; ++t) {
      float c[NL];
#pragma unroll
      for (int i = 0; i < NL; ++i) c[i] = s[i] + tc[i];
      // fused value/argmax tree (select-tree == fmax-tree for non-NaN,
      // ties keep lowest index like jnp.argmax)
      const bool b01 = c[0] >= c[1], b23 = c[2] >= c[3];
      const bool b45 = c[4] >= c[5], b67 = c[6] >= c[7];
      const float v01 = b01 ? c[0] : c[1]; const int i01 = b01 ? 0 : 1;
      const float v23 = b23 ? c[2] : c[3]; const int i23 = b23 ? 2 : 3;
      const float v45 = b45 ? c[4] : c[5]; const int i45 = b45 ? 4 : 5;
      const float v67 = b67 ? c[6] : c[7]; const int i67 = b67 ? 6 : 7;
      const bool bA = v01 >= v23, bB = v45 >= v67;
      const float vA = bA ? v01 : v23; const int iA = bA ? i01 : i23;
      const float vB = bB ? v45 : v67; const int iB = bB ? i45 : i67;
      const bool bC = vA >= vB;
      const float vC = bC ? vA : vB; const int iC = bC ? iA : iB;
      const bool bD = vC >= c[8];
      const float best = bD ? vC : c[8];
      const int   arg  = bD ? iC : 8;
      bp_s[t * NL + tid] = (unsigned char)arg;
      const float nxt = best + eA;
#pragma unroll
      for (int i = 0; i < NL; ++i) s[i] = readlane_f(nxt, i);
      eA = eB; eB = eC; eC = eD;
      eD = emb_s[(t + 4) * NL + j];
    }
    float bv = s[0] + end_t[0];
    int   bl = 0;
#pragma unroll
    for (int i = 1; i < NL; ++i) {
      const float cc = s[i] + end_t[i];
      if (cc > bv) { bv = cc; bl = i; }
    }
    __syncthreads();

    // backtrace: chunked map composition
    uint64_t C = 0x876543210ULL;
#pragma unroll
    for (int k = 1; k <= 8; ++k) {
      const int t = 8 * tid + k;
      uint64_t nc = 0;
#pragma unroll
      for (int x = 0; x < 9; ++x) {
        const int g = bp_s[t * NL + x] & 15;
        nc |= ((C >> (4 * g)) & 15ULL) << (4 * x);
      }
      C = (t < len) ? nc : C;
    }
    const uint32_t Clo = (uint32_t)C, Chi = (uint32_t)(C >> 32);
    uint32_t cur = (uint32_t)bl;
    int bnd = 0;
#pragma unroll
    for (int c = 63; c >= 0; --c) {
      bnd = (tid == c) ? (int)cur : bnd;
      const uint32_t lo = (uint32_t)__builtin_amdgcn_readlane((int)Clo, c);
      const uint32_t hi = (uint32_t)__builtin_amdgcn_readlane((int)Chi, c);
      const uint64_t cc = ((uint64_t)hi << 32) | lo;
      cur = (uint32_t)((cc >> (4 * cur)) & 15u);
    }
    int tag = bnd;
#pragma unroll
    for (int k = 8; k >= 1; --k) {
      const int t = 8 * tid + k;
      const int tt = (t < 512) ? t : 511;
      const int nt = bp_s[tt * NL + tag];
      tag = (t < len) ? nt : tag;
      tags_s[t - 1] = (unsigned char)tag;
    }
    __syncthreads();
    for (int i = tid; i < EMN; i += 64) {
      const int t = i / NL;
      const int l = i - t * NL;
      out[1 + (size_t)b * EMN + i] =
          (t < len && l == (int)tags_s[t]) ? 1.0f : 0.0f;
    }

  } else if (blk < 128) {
    // ================= numerator =================
    const int b   = blk - 64;
    const int len = lens[b];
    const float* emb = logits + (size_t)b * EMN;
    for (int t = tid; t < SS; t += 64) {
      const int v = labels[b * SS + t];
      lab[t] = (unsigned char)((v == -100) ? 0 : v);
    }
    __syncthreads();
    float contrib = 0.0f;
    for (int t = tid; t < SS; t += 64) {
      if (t >= 1 && t < len)
        contrib += emb[t * NL + lab[t]] + trans[lab[t - 1] * NL + lab[t]];
    }
#pragma unroll
    for (int off = 32; off >= 1; off >>= 1)
      contrib += __shfl_xor(contrib, off, 64);
    if (tid == 0) {
      const int l0 = lab[0];
      num_den[b] = start_t[l0] + emb[l0] + contrib + end_t[lab[len - 1]];
    }

  } else {
    // ================= lognorm segment scan, 3 chains per wave =================
    const int id   = blk - 128;        // 0..1535
    const int pair = id / 3;           // (b, sg)
    const int wv   = id - pair * 3;    // which e-triple
    const int b    = pair >> 3;
    const int sg   = pair & 7;
    const int e0   = 3 * wv;           // chains e0, e0+1, e0+2
    const int len  = lens[b];
    const float* emb = logits + (size_t)b * EMN;
    float tc[NL];
#pragma unroll
    for (int i = 0; i < NL; ++i) tc[i] = trans[i * NL + j];
    float s0[NL], s1[NL], s2[NL];
#pragma unroll
    for (int i = 0; i < NL; ++i) {
      s0[i] = (i == e0)     ? 0.0f : NEG;
      s1[i] = (i == e0 + 1) ? 0.0f : NEG;
      s2[i] = (i == e0 + 2) ? 0.0f : NEG;
    }
    float my0 = (j == e0)     ? 0.0f : NEG;
    float my1 = (j == e0 + 1) ? 0.0f : NEG;
    float my2 = (j == e0 + 2) ? 0.0f : NEG;
    const int tbeg  = 64 * sg + 1;
    const int tlast = (64 * sg + 64 < 511) ? 64 * sg + 64 : 511;
    float eA = emb[tbeg * NL + j],       eB = emb[(tbeg + 1) * NL + j];
    float eC = emb[(tbeg + 2) * NL + j], eD = emb[(tbeg + 3) * NL + j];
    for (int t = tbeg; t <= tlast; ++t) {
      if (t >= len) break;             // prefix mask: rest are identity steps
      float c0[NL], c1[NL], c2[NL];
#pragma unroll
      for (int i = 0; i < NL; ++i) {
        c0[i] = s0[i] + tc[i];
        c1[i] = s1[i] + tc[i];
        c2[i] = s2[i] + tc[i];
      }
      const float m0 = fmaxf(fmaxf(fmaxf(fmaxf(c0[0], c0[1]), fmaxf(c0[2], c0[3])),
                                   fmaxf(fmaxf(c0[4], c0[5]), fmaxf(c0[6], c0[7]))), c0[8]);
      const float m1 = fmaxf(fmaxf(fmaxf(fmaxf(c1[0], c1[1]), fmaxf(c1[2], c1[3])),
                                   fmaxf(fmaxf(c1[4], c1[5]), fmaxf(c1[6], c1[7]))), c1[8]);
      const float m2 = fmaxf(fmaxf(fmaxf(fmaxf(c2[0], c2[1]), fmaxf(c2[2], c2[3])),
                                   fmaxf(fmaxf(c2[4], c2[5]), fmaxf(c2[6], c2[7]))), c2[8]);
      float u0 = 0.0f, u1 = 0.0f, u2 = 0.0f;
#pragma unroll
      for (int i = 0; i < NL; ++i) {
        u0 += __expf(c0[i] - m0);
        u1 += __expf(c1[i] - m1);
        u2 += __expf(c2[i] - m2);
      }
      my0 = m0 + __logf(u0) + eA;
      my1 = m1 + __logf(u1) + eA;
      my2 = m2 + __logf(u2) + eA;
#pragma unroll
      for (int i = 0; i < NL; ++i) {
        s0[i] = readlane_f(my0, i);
        s1[i] = readlane_f(my1, i);
        s2[i] = readlane_f(my2, i);
      }
      eA = eB; eB = eC; eC = eD;
      eD = emb[(t + 4) * NL + j];
    }
    if (tid < NL) {
      float* M = segmat + (size_t)(b * NSEG + sg) * 81;
      M[(e0    ) * NL + tid] = my0;
      M[(e0 + 1) * NL + tid] = my1;
      M[(e0 + 2) * NL + tid] = my2;
    }
  }
}

// ---------------------------------------------------------------------------
// Kernel 3: combine + loss — per batch, chain the 8 segment matrices, get
// den = logsumexp(v + end_t), then atomically accumulate (den-num)/64.
// ---------------------------------------------------------------------------
__global__ __launch_bounds__(64) void combine_kernel(
    const float* __restrict__ logits, const float* __restrict__ segmat,
    const float* __restrict__ start_t, const float* __restrict__ end_t,
    const float* __restrict__ num_den, float* __restrict__ out) {
  const int b   = blockIdx.x;
  const int tid = threadIdx.x;
  const int j   = (tid < NL) ? tid : NL - 1;
  float s[NL];
#pragma unroll
  for (int i = 0; i < NL; ++i) s[i] = start_t[i] + logits[(size_t)b * EMN + i];
  float mcur[NL], mnxt[NL];
  {
    const float* M = segmat + (size_t)(b * NSEG) * 81;
#pragma unroll
    for (int i = 0; i < NL; ++i) mcur[i] = M[i * NL + j];
  }
  for (int sg = 0; sg < NSEG; ++sg) {
    if (sg + 1 < NSEG) {
      const float* M = segmat + (size_t)(b * NSEG + sg + 1) * 81;
#pragma unroll
      for (int i = 0; i < NL; ++i) mnxt[i] = M[i * NL + j];
    }
    float c[NL];
#pragma unroll
    for (int i = 0; i < NL; ++i) c[i] = s[i] + mcur[i];
    const float x01 = fmaxf(c[0], c[1]), x23 = fmaxf(c[2], c[3]);
    const float x45 = fmaxf(c[4], c[5]), x67 = fmaxf(c[6], c[7]);
    const float m = fmaxf(fmaxf(fmaxf(x01, x23), fmaxf(x45, x67)), c[8]);
    float sum = 0.0f;
#pragma unroll
    for (int i = 0; i < NL; ++i) sum += __expf(c[i] - m);
    const float nxt = m + __logf(sum);
#pragma unroll
    for (int i = 0; i < NL; ++i) s[i] = readlane_f(nxt, i);
#pragma unroll
    for (int i = 0; i < NL; ++i) mcur[i] = mnxt[i];
  }
  float c[NL];
#pragma unroll
  for (int i = 0; i < NL; ++i) c[i] = s[i] + end_t[i];
  const float x01 = fmaxf(c[0], c[1]), x23 = fmaxf(c[2], c[3]);
  const float x45 = fmaxf(c[4], c[5]), x67 = fmaxf(c[6], c[7]);
  const float m = fmaxf(fmaxf(fmaxf(x01, x23), fmaxf(x45, x67)), c[8]);
  float sum = 0.0f;
#pragma unroll
  for (int i = 0; i < NL; ++i) sum += __expf(c[i] - m);
  if (tid == 0) {
    const float den = m + __logf(sum);
    atomicAdd(out, (den - num_den[b]) * (1.0f / 64.0f));
  }
}

extern "C" void kernel_launch(void* const* d_in, const int* in_sizes, int n_in,
                              void* d_out, int out_size, void* d_ws, size_t ws_size,
                              hipStream_t stream) {
  const float* hidden  = (const float*)d_in[0];
  const int*   mask    = (const int*)d_in[1];
  const int*   labels  = (const int*)d_in[2];
  const float* W       = (const float*)d_in[3];
  const float* bias    = (const float*)d_in[4];
  const float* start_t = (const float*)d_in[5];
  const float* end_t   = (const float*)d_in[6];
  const float* trans   = (const float*)d_in[7];
  float* out = (float*)d_out;

  float* logits  = (float*)d_ws;                      // 294912 floats
  float* segmat  = logits + (size_t)NROWS * NL;       // 64*8*81 floats
  float* num_den = segmat + (size_t)BB * NSEG * 81;   // 64 floats (num)
  int*   lens    = (int*)(num_den + 128);             // 64 ints

  logits_kernel<<<2048, 256, 0, stream>>>(hidden, W, bias, mask, logits, lens, out);
  scan_kernel<<<1664, 64, 0, stream>>>(logits, labels, start_t, end_t, trans,
                                       out, num_den, lens, segmat);
  combine_kernel<<<64, 64, 0, stream>>>(logits, segmat, start_t, end_t,
                                        num_den, out);
}

// Round 2
// 249.456 us; speedup vs baseline: 1.0296x; 1.0285x over previous
//
#include <hip/hip_runtime.h>
#include <hip/hip_bf16.h>
#include <stdint.h>

constexpr int BB  = 64;    // batch
constexpr int SS  = 512;   // seq len
constexpr int HH  = 768;   // hidden
constexpr int NL  = 9;     // labels
constexpr int NROWS = BB * SS;          // 32768
constexpr int EMN   = SS * NL;          // 4608 emissions per batch
constexpr int NSEG  = 8;                // time segments for parallel lognorm
constexpr float NEG  = -1e30f;

__device__ __forceinline__ float readlane_f(float v, int lane) {
  union { float f; int i; } u;
  u.f = v;
  u.i = __builtin_amdgcn_readlane(u.i, lane);
  return u.f;
}

// 3-input max, single instruction, depth-2 trees for 9-way max.
// EXACT: float max is associative/commutative for finite inputs (no rounding),
// so reassociating the max tree cannot change any value or argmax decision.
__device__ __forceinline__ float max3f(float a, float b, float c) {
  float d;
  asm("v_max3_f32 %0, %1, %2, %3" : "=v"(d) : "v"(a), "v"(b), "v"(c));
  return d;
}

__device__ __forceinline__ float max9f(const float* c) {
  return max3f(max3f(c[0], c[1], c[2]),
               max3f(c[3], c[4], c[5]),
               max3f(c[6], c[7], c[8]));
}

// ---------------------------------------------------------------------------
// Kernel 1: logits[b,s,l] = hidden[b,s,:] @ W[:,l] + bias[l]
// One wave per 4 rows, all 4 in flight (butterfly chains interleave).
// Blocks 0..63 additionally compute lens[b]. Block 0 zeroes the loss acc.
// ---------------------------------------------------------------------------
__global__ __launch_bounds__(256, 2) void logits_kernel(
    const float* __restrict__ hidden, const float* __restrict__ W,
    const float* __restrict__ bias, const int* __restrict__ mask,
    float* __restrict__ logits, int* __restrict__ lens,
    float* __restrict__ out) {
  const int lane = threadIdx.x & 63;
  const int wid  = blockIdx.x * 4 + (threadIdx.x >> 6);   // 8192 waves

  if (blockIdx.x == 0 && threadIdx.x == 0) out[0] = 0.0f;

  if (blockIdx.x < 64 && threadIdx.x < 64) {
    const int4* mp = (const int4*)(mask + blockIdx.x * SS);
    const int4 a = mp[threadIdx.x];
    const int4 c = mp[threadIdx.x + 64];
    int lsum = a.x + a.y + a.z + a.w + c.x + c.y + c.z + c.w;
#pragma unroll
    for (int off = 32; off >= 1; off >>= 1) lsum += __shfl_xor(lsum, off, 64);
    if (threadIdx.x == 0) lens[blockIdx.x] = lsum;
  }

  float w[3][4][NL];
#pragma unroll
  for (int j = 0; j < 3; ++j)
#pragma unroll
    for (int k = 0; k < 4; ++k) {
      const int r = lane * 4 + j * 256 + k;
#pragma unroll
      for (int l = 0; l < NL; ++l) w[j][k][l] = W[r * NL + l];
    }
  const float my_bias = (lane < NL) ? bias[lane] : 0.0f;

  // 4 rows in flight
  float4 h[4][3];
#pragma unroll
  for (int r = 0; r < 4; ++r) {
    const float4* hp = (const float4*)(hidden + (size_t)(wid + r * 8192) * HH);
#pragma unroll
    for (int j = 0; j < 3; ++j) h[r][j] = hp[lane + j * 64];
  }
  float acc[4][NL];
#pragma unroll
  for (int r = 0; r < 4; ++r)
#pragma unroll
    for (int l = 0; l < NL; ++l) acc[r][l] = 0.0f;
#pragma unroll
  for (int r = 0; r < 4; ++r)
#pragma unroll
    for (int j = 0; j < 3; ++j)
#pragma unroll
      for (int l = 0; l < NL; ++l)
        acc[r][l] += h[r][j].x * w[j][0][l] + h[r][j].y * w[j][1][l] +
                     h[r][j].z * w[j][2][l] + h[r][j].w * w[j][3][l];
#pragma unroll
  for (int off = 32; off >= 1; off >>= 1)
#pragma unroll
    for (int r = 0; r < 4; ++r)
#pragma unroll
      for (int l = 0; l < NL; ++l)
        acc[r][l] += __shfl_xor(acc[r][l], off, 64);
  if (lane < NL) {
#pragma unroll
    for (int r = 0; r < 4; ++r) {
      float v = acc[r][0];
#pragma unroll
      for (int l = 1; l < NL; ++l) if (lane == l) v = acc[r][l];
      logits[(size_t)(wid + r * 8192) * NL + lane] = v + my_bias;
    }
  }
}

// ---------------------------------------------------------------------------
// Kernel 2: scan kernel, 1664 one-wave blocks.
//   blk   0..  63 : viterbi — critical path is now add -> max3 depth-2 ->
//                   add -> readlane; the argmax select tree runs OFF-path.
//   blk  64.. 127 : numerator (gold-path score), parallel over t
//   blk 128..1663 : lognorm segment scans, 3 basis chains per wave (ILP-3)
// ---------------------------------------------------------------------------
__global__ __launch_bounds__(64) void scan_kernel(
    const float* __restrict__ logits, const int* __restrict__ labels,
    const float* __restrict__ start_t, const float* __restrict__ end_t,
    const float* __restrict__ trans, float* __restrict__ out,
    float* __restrict__ num_den, const int* __restrict__ lens,
    float* __restrict__ segmat) {
  __shared__ float4 embv[1161];                 // 4644 floats (pad covers t+4 prefetch)
  __shared__ unsigned char bp_s[EMN + 80];
  __shared__ unsigned char tags_s[SS];
  __shared__ unsigned char lab[SS];

  const int blk = blockIdx.x;
  const int tid = threadIdx.x;
  const int j   = (tid < NL) ? tid : NL - 1;

  if (blk < 64) {
    // ================= viterbi =================
    __builtin_amdgcn_s_setprio(1);              // critical serial chain: win arbitration
    const int b   = blk;
    const int len = lens[b];
    const float* emb = logits + (size_t)b * EMN;

    // stage this batch's emissions into LDS (one coalesced burst)
    {
      const float4* src = (const float4*)emb;
#pragma unroll
      for (int i = 0; i < 18; ++i) embv[tid + i * 64] = src[tid + i * 64];
    }
    __syncthreads();
    const float* emb_s = (const float*)embv;

    float tc[NL];
#pragma unroll
    for (int i = 0; i < NL; ++i) tc[i] = trans[i * NL + j];
    float s[NL];
#pragma unroll
    for (int i = 0; i < NL; ++i) s[i] = start_t[i] + emb_s[i];
    float eA = emb_s[1 * NL + j], eB = emb_s[2 * NL + j];
    float eC = emb_s[3 * NL + j], eD = emb_s[4 * NL + j];
    for (int t = 1; t < len; ++t) {
      float c[NL];
#pragma unroll
      for (int i = 0; i < NL; ++i) c[i] = s[i] + tc[i];
      // CRITICAL PATH: value max via depth-2 max3 (exact reassociation)
      const float best = max9f(c);
      const float nxt  = best + eA;
      // OFF-PATH: argmax select tree (bit-identical tie-breaking: lowest idx)
      {
        const bool b01 = c[0] >= c[1], b23 = c[2] >= c[3];
        const bool b45 = c[4] >= c[5], b67 = c[6] >= c[7];
        const float v01 = b01 ? c[0] : c[1]; const int i01 = b01 ? 0 : 1;
        const float v23 = b23 ? c[2] : c[3]; const int i23 = b23 ? 2 : 3;
        const float v45 = b45 ? c[4] : c[5]; const int i45 = b45 ? 4 : 5;
        const float v67 = b67 ? c[6] : c[7]; const int i67 = b67 ? 6 : 7;
        const bool bA = v01 >= v23, bB = v45 >= v67;
        const float vA = bA ? v01 : v23; const int iA = bA ? i01 : i23;
        const float vB = bB ? v45 : v67; const int iB = bB ? i45 : i67;
        const bool bC = vA >= vB;
        const float vC = bC ? vA : vB; const int iC = bC ? iA : iB;
        const bool bD = vC >= c[8];
        const int arg = bD ? iC : 8;
        bp_s[t * NL + tid] = (unsigned char)arg;
      }
#pragma unroll
      for (int i = 0; i < NL; ++i) s[i] = readlane_f(nxt, i);
      eA = eB; eB = eC; eC = eD;
      eD = emb_s[(t + 4) * NL + j];
    }
    float bv = s[0] + end_t[0];
    int   bl = 0;
#pragma unroll
    for (int i = 1; i < NL; ++i) {
      const float cc = s[i] + end_t[i];
      if (cc > bv) { bv = cc; bl = i; }
    }
    __syncthreads();

    // backtrace: chunked map composition
    uint64_t C = 0x876543210ULL;
#pragma unroll
    for (int k = 1; k <= 8; ++k) {
      const int t = 8 * tid + k;
      uint64_t nc = 0;
#pragma unroll
      for (int x = 0; x < 9; ++x) {
        const int g = bp_s[t * NL + x] & 15;
        nc |= ((C >> (4 * g)) & 15ULL) << (4 * x);
      }
      C = (t < len) ? nc : C;
    }
    const uint32_t Clo = (uint32_t)C, Chi = (uint32_t)(C >> 32);
    uint32_t cur = (uint32_t)bl;
    int bnd = 0;
#pragma unroll
    for (int c = 63; c >= 0; --c) {
      bnd = (tid == c) ? (int)cur : bnd;
      const uint32_t lo = (uint32_t)__builtin_amdgcn_readlane((int)Clo, c);
      const uint32_t hi = (uint32_t)__builtin_amdgcn_readlane((int)Chi, c);
      const uint64_t cc = ((uint64_t)hi << 32) | lo;
      cur = (uint32_t)((cc >> (4 * cur)) & 15u);
    }
    int tag = bnd;
#pragma unroll
    for (int k = 8; k >= 1; --k) {
      const int t = 8 * tid + k;
      const int tt = (t < 512) ? t : 511;
      const int nt = bp_s[tt * NL + tag];
      tag = (t < len) ? nt : tag;
      tags_s[t - 1] = (unsigned char)tag;
    }
    __syncthreads();
    for (int i = tid; i < EMN; i += 64) {
      const int t = i / NL;
      const int l = i - t * NL;
      out[1 + (size_t)b * EMN + i] =
          (t < len && l == (int)tags_s[t]) ? 1.0f : 0.0f;
    }

  } else if (blk < 128) {
    // ================= numerator =================
    const int b   = blk - 64;
    const int len = lens[b];
    const float* emb = logits + (size_t)b * EMN;
    for (int t = tid; t < SS; t += 64) {
      const int v = labels[b * SS + t];
      lab[t] = (unsigned char)((v == -100) ? 0 : v);
    }
    __syncthreads();
    float contrib = 0.0f;
    for (int t = tid; t < SS; t += 64) {
      if (t >= 1 && t < len)
        contrib += emb[t * NL + lab[t]] + trans[lab[t - 1] * NL + lab[t]];
    }
#pragma unroll
    for (int off = 32; off >= 1; off >>= 1)
      contrib += __shfl_xor(contrib, off, 64);
    if (tid == 0) {
      const int l0 = lab[0];
      num_den[b] = start_t[l0] + emb[l0] + contrib + end_t[lab[len - 1]];
    }

  } else {
    // ================= lognorm segment scan, 3 chains per wave =================
    const int id   = blk - 128;        // 0..1535
    const int pair = id / 3;           // (b, sg)
    const int wv   = id - pair * 3;    // which e-triple
    const int b    = pair >> 3;
    const int sg   = pair & 7;
    const int e0   = 3 * wv;           // chains e0, e0+1, e0+2
    const int len  = lens[b];
    const float* emb = logits + (size_t)b * EMN;
    float tc[NL];
#pragma unroll
    for (int i = 0; i < NL; ++i) tc[i] = trans[i * NL + j];
    float s0[NL], s1[NL], s2[NL];
#pragma unroll
    for (int i = 0; i < NL; ++i) {
      s0[i] = (i == e0)     ? 0.0f : NEG;
      s1[i] = (i == e0 + 1) ? 0.0f : NEG;
      s2[i] = (i == e0 + 2) ? 0.0f : NEG;
    }
    float my0 = (j == e0)     ? 0.0f : NEG;
    float my1 = (j == e0 + 1) ? 0.0f : NEG;
    float my2 = (j == e0 + 2) ? 0.0f : NEG;
    const int tbeg  = 64 * sg + 1;
    const int tlast = (64 * sg + 64 < 511) ? 64 * sg + 64 : 511;
    float eA = emb[tbeg * NL + j],       eB = emb[(tbeg + 1) * NL + j];
    float eC = emb[(tbeg + 2) * NL + j], eD = emb[(tbeg + 3) * NL + j];
    for (int t = tbeg; t <= tlast; ++t) {
      if (t >= len) break;             // prefix mask: rest are identity steps
      float c0[NL], c1[NL], c2[NL];
#pragma unroll
      for (int i = 0; i < NL; ++i) {
        c0[i] = s0[i] + tc[i];
        c1[i] = s1[i] + tc[i];
        c2[i] = s2[i] + tc[i];
      }
      // max via depth-2 max3 (exact); exp-sum order untouched (bit-identical)
      const float m0 = max9f(c0);
      const float m1 = max9f(c1);
      const float m2 = max9f(c2);
      float u0 = 0.0f, u1 = 0.0f, u2 = 0.0f;
#pragma unroll
      for (int i = 0; i < NL; ++i) {
        u0 += __expf(c0[i] - m0);
        u1 += __expf(c1[i] - m1);
        u2 += __expf(c2[i] - m2);
      }
      my0 = m0 + __logf(u0) + eA;
      my1 = m1 + __logf(u1) + eA;
      my2 = m2 + __logf(u2) + eA;
#pragma unroll
      for (int i = 0; i < NL; ++i) {
        s0[i] = readlane_f(my0, i);
        s1[i] = readlane_f(my1, i);
        s2[i] = readlane_f(my2, i);
      }
      eA = eB; eB = eC; eC = eD;
      eD = emb[(t + 4) * NL + j];
    }
    if (tid < NL) {
      float* M = segmat + (size_t)(b * NSEG + sg) * 81;
      M[(e0    ) * NL + tid] = my0;
      M[(e0 + 1) * NL + tid] = my1;
      M[(e0 + 2) * NL + tid] = my2;
    }
  }
}

// ---------------------------------------------------------------------------
// Kernel 3: combine + loss — per batch, chain the 8 segment matrices, get
// den = logsumexp(v + end_t), then atomically accumulate (den-num)/64.
// ---------------------------------------------------------------------------
__global__ __launch_bounds__(64) void combine_kernel(
    const float* __restrict__ logits, const float* __restrict__ segmat,
    const float* __restrict__ start_t, const float* __restrict__ end_t,
    const float* __restrict__ num_den, float* __restrict__ out) {
  const int b   = blockIdx.x;
  const int tid = threadIdx.x;
  const int j   = (tid < NL) ? tid : NL - 1;
  float s[NL];
#pragma unroll
  for (int i = 0; i < NL; ++i) s[i] = start_t[i] + logits[(size_t)b * EMN + i];
  float mcur[NL], mnxt[NL];
  {
    const float* M = segmat + (size_t)(b * NSEG) * 81;
#pragma unroll
    for (int i = 0; i < NL; ++i) mcur[i] = M[i * NL + j];
  }
  for (int sg = 0; sg < NSEG; ++sg) {
    if (sg + 1 < NSEG) {
      const float* M = segmat + (size_t)(b * NSEG + sg + 1) * 81;
#pragma unroll
      for (int i = 0; i < NL; ++i) mnxt[i] = M[i * NL + j];
    }
    float c[NL];
#pragma unroll
    for (int i = 0; i < NL; ++i) c[i] = s[i] + mcur[i];
    const float m = max9f(c);
    float sum = 0.0f;
#pragma unroll
    for (int i = 0; i < NL; ++i) sum += __expf(c[i] - m);
    const float nxt = m + __logf(sum);
#pragma unroll
    for (int i = 0; i < NL; ++i) s[i] = readlane_f(nxt, i);
#pragma unroll
    for (int i = 0; i < NL; ++i) mcur[i] = mnxt[i];
  }
  float c[NL];
#pragma unroll
  for (int i = 0; i < NL; ++i) c[i] = s[i] + end_t[i];
  const float m = max9f(c);
  float sum = 0.0f;
#pragma unroll
  for (int i = 0; i < NL; ++i) sum += __expf(c[i] - m);
  if (tid == 0) {
    const float den = m + __logf(sum);
    atomicAdd(out, (den - num_den[b]) * (1.0f / 64.0f));
  }
}

extern "C" void kernel_launch(void* const* d_in, const int* in_sizes, int n_in,
                              void* d_out, int out_size, void* d_ws, size_t ws_size,
                              hipStream_t stream) {
  const float* hidden  = (const float*)d_in[0];
  const int*   mask    = (const int*)d_in[1];
  const int*   labels  = (const int*)d_in[2];
  const float* W       = (const float*)d_in[3];
  const float* bias    = (const float*)d_in[4];
  const float* start_t = (const float*)d_in[5];
  const float* end_t   = (const float*)d_in[6];
  const float* trans   = (const float*)d_in[7];
  float* out = (float*)d_out;

  float* logits  = (float*)d_ws;                      // 294912 floats
  float* segmat  = logits + (size_t)NROWS * NL;       // 64*8*81 floats
  float* num_den = segmat + (size_t)BB * NSEG * 81;   // 64 floats (num)
  int*   lens    = (int*)(num_den + 128);             // 64 ints

  logits_kernel<<<2048, 256, 0, stream>>>(hidden, W, bias, mask, logits, lens, out);
  scan_kernel<<<1664, 64, 0, stream>>>(logits, labels, start_t, end_t, trans,
                                       out, num_den, lens, segmat);
  combine_kernel<<<64, 64, 0, stream>>>(logits, segmat, start_t, end_t,
                                        num_den, out);
}

// Round 3
// 240.919 us; speedup vs baseline: 1.0661x; 1.0354x over previous
//
#include <hip/hip_runtime.h>
#include <hip/hip_bf16.h>
#include <stdint.h>

constexpr int BB  = 64;    // batch
constexpr int SS  = 512;   // seq len
constexpr int HH  = 768;   // hidden
constexpr int NL  = 9;     // labels
constexpr int NROWS = BB * SS;          // 32768
constexpr int EMN   = SS * NL;          // 4608 emissions per batch
constexpr int NSEG  = 8;                // time segments for parallel lognorm
constexpr float NEG  = -1e30f;

__device__ __forceinline__ float readlane_f(float v, int lane) {
  union { float f; int i; } u;
  u.f = v;
  u.i = __builtin_amdgcn_readlane(u.i, lane);
  return u.f;
}

// 3-input max, single instruction, depth-2 trees for 9-way max.
// EXACT: float max is associative/commutative for finite inputs (no rounding),
// so reassociating the max tree cannot change any value or argmax decision.
__device__ __forceinline__ float max3f(float a, float b, float c) {
  float d;
  asm("v_max3_f32 %0, %1, %2, %3" : "=v"(d) : "v"(a), "v"(b), "v"(c));
  return d;
}

__device__ __forceinline__ float max9f(const float* c) {
  return max3f(max3f(c[0], c[1], c[2]),
               max3f(c[3], c[4], c[5]),
               max3f(c[6], c[7], c[8]));
}

// ---------------------------------------------------------------------------
// Kernel 1: logits[b,s,l] = hidden[b,s,:] @ W[:,l] + bias[l]
// One wave per 4 rows, all 4 in flight (butterfly chains interleave).
// Blocks 0..63 additionally compute lens[b]. Block 0 zeroes the loss acc.
// ---------------------------------------------------------------------------
__global__ __launch_bounds__(256, 2) void logits_kernel(
    const float* __restrict__ hidden, const float* __restrict__ W,
    const float* __restrict__ bias, const int* __restrict__ mask,
    float* __restrict__ logits, int* __restrict__ lens,
    float* __restrict__ out) {
  const int lane = threadIdx.x & 63;
  const int wid  = blockIdx.x * 4 + (threadIdx.x >> 6);   // 8192 waves

  if (blockIdx.x == 0 && threadIdx.x == 0) out[0] = 0.0f;

  if (blockIdx.x < 64 && threadIdx.x < 64) {
    const int4* mp = (const int4*)(mask + blockIdx.x * SS);
    const int4 a = mp[threadIdx.x];
    const int4 c = mp[threadIdx.x + 64];
    int lsum = a.x + a.y + a.z + a.w + c.x + c.y + c.z + c.w;
#pragma unroll
    for (int off = 32; off >= 1; off >>= 1) lsum += __shfl_xor(lsum, off, 64);
    if (threadIdx.x == 0) lens[blockIdx.x] = lsum;
  }

  float w[3][4][NL];
#pragma unroll
  for (int j = 0; j < 3; ++j)
#pragma unroll
    for (int k = 0; k < 4; ++k) {
      const int r = lane * 4 + j * 256 + k;
#pragma unroll
      for (int l = 0; l < NL; ++l) w[j][k][l] = W[r * NL + l];
    }
  const float my_bias = (lane < NL) ? bias[lane] : 0.0f;

  // 4 rows in flight
  float4 h[4][3];
#pragma unroll
  for (int r = 0; r < 4; ++r) {
    const float4* hp = (const float4*)(hidden + (size_t)(wid + r * 8192) * HH);
#pragma unroll
    for (int j = 0; j < 3; ++j) h[r][j] = hp[lane + j * 64];
  }
  float acc[4][NL];
#pragma unroll
  for (int r = 0; r < 4; ++r)
#pragma unroll
    for (int l = 0; l < NL; ++l) acc[r][l] = 0.0f;
#pragma unroll
  for (int r = 0; r < 4; ++r)
#pragma unroll
    for (int j = 0; j < 3; ++j)
#pragma unroll
      for (int l = 0; l < NL; ++l)
        acc[r][l] += h[r][j].x * w[j][0][l] + h[r][j].y * w[j][1][l] +
                     h[r][j].z * w[j][2][l] + h[r][j].w * w[j][3][l];
#pragma unroll
  for (int off = 32; off >= 1; off >>= 1)
#pragma unroll
    for (int r = 0; r < 4; ++r)
#pragma unroll
      for (int l = 0; l < NL; ++l)
        acc[r][l] += __shfl_xor(acc[r][l], off, 64);
  if (lane < NL) {
#pragma unroll
    for (int r = 0; r < 4; ++r) {
      float v = acc[r][0];
#pragma unroll
      for (int l = 1; l < NL; ++l) if (lane == l) v = acc[r][l];
      logits[(size_t)(wid + r * 8192) * NL + lane] = v + my_bias;
    }
  }
}

// ---------------------------------------------------------------------------
// Kernel 2: scan kernel, 1664 one-wave blocks.
//   blk   0..  63 : viterbi — NO per-step DS ops: emissions double-buffered
//                   in registers (8-step blocks, global loads), backpointers
//                   packed 8x4-bit per register, one ds_write_b32 / 8 steps.
//   blk  64.. 127 : numerator (gold-path score), parallel over t
//   blk 128..1663 : lognorm segment scans, 3 basis chains per wave (ILP-3)
// LDS is now ~3.3 KB/block (was 24.6 KB) -> full occupancy for lognorm pool.
// ---------------------------------------------------------------------------
__global__ __launch_bounds__(64) void scan_kernel(
    const float* __restrict__ logits, const int* __restrict__ labels,
    const float* __restrict__ start_t, const float* __restrict__ end_t,
    const float* __restrict__ trans, float* __restrict__ out,
    float* __restrict__ num_den, const int* __restrict__ lens,
    float* __restrict__ segmat) {
  __shared__ uint32_t bpw[64 * NL];             // packed backpointers: 2304 B
  __shared__ unsigned char tags_s[SS];
  __shared__ unsigned char lab[SS];

  const int blk = blockIdx.x;
  const int tid = threadIdx.x;
  const int j   = (tid < NL) ? tid : NL - 1;

  if (blk < 64) {
    // ================= viterbi =================
    __builtin_amdgcn_s_setprio(1);              // critical serial chain: win arbitration
    const int b   = blk;
    const int len = lens[b];
    const float* emb = logits + (size_t)b * EMN;

    float tc[NL];
#pragma unroll
    for (int i = 0; i < NL; ++i) tc[i] = trans[i * NL + j];
    float s[NL];
#pragma unroll
    for (int i = 0; i < NL; ++i) s[i] = start_t[i] + emb[i];

    // double-buffered emission registers: block tb covers t = 8*tb+1 .. 8*tb+8
    float e0[8], e1[8];
#pragma unroll
    for (int k = 0; k < 8; ++k) e0[k] = emb[(1 + k) * NL + j];

    for (int tb = 0; tb < 64; ++tb) {
      const int tbase = 8 * tb;
      if (tbase + 1 >= len) break;
      if (tb < 63) {
        // prefetch next block's emissions (consumed a full block later;
        // note: tb==62 prefetches up to t=512 which reads 9 floats past this
        // batch's logits -- lands in segmat region of the same workspace,
        // harmless and never consumed (t=512 >= len always).
#pragma unroll
        for (int k = 0; k < 8; ++k) e1[k] = emb[(tbase + 9 + k) * NL + j];
      }
      uint32_t wpk = 0;
#pragma unroll
      for (int k = 0; k < 8; ++k) {
        const int t = tbase + 1 + k;
        if (t < len) {                           // wave-uniform (len in SGPR)
          float c[NL];
#pragma unroll
          for (int i = 0; i < NL; ++i) c[i] = s[i] + tc[i];
          // CRITICAL PATH: value max via depth-2 max3 (exact reassociation)
          const float best = max9f(c);
          const float nxt  = best + e0[k];
          // OFF-PATH: argmax select tree (ref tie-breaking: lowest idx)
          {
            const bool b01 = c[0] >= c[1], b23 = c[2] >= c[3];
            const bool b45 = c[4] >= c[5], b67 = c[6] >= c[7];
            const float v01 = b01 ? c[0] : c[1]; const int i01 = b01 ? 0 : 1;
            const float v23 = b23 ? c[2] : c[3]; const int i23 = b23 ? 2 : 3;
            const float v45 = b45 ? c[4] : c[5]; const int i45 = b45 ? 4 : 5;
            const float v67 = b67 ? c[6] : c[7]; const int i67 = b67 ? 6 : 7;
            const bool bA = v01 >= v23, bB = v45 >= v67;
            const float vA = bA ? v01 : v23; const int iA = bA ? i01 : i23;
            const float vB = bB ? v45 : v67; const int iB = bB ? i45 : i67;
            const bool bC = vA >= vB;
            const float vC = bC ? vA : vB; const int iC = bC ? iA : iB;
            const bool bD = vC >= c[8];
            const int arg = bD ? iC : 8;
            wpk |= (uint32_t)arg << (4 * k);
          }
#pragma unroll
          for (int i = 0; i < NL; ++i) s[i] = readlane_f(nxt, i);
        }
      }
      if (tid < NL) bpw[tb * NL + tid] = wpk;
#pragma unroll
      for (int k = 0; k < 8; ++k) e0[k] = e1[k];
    }
    float bv = s[0] + end_t[0];
    int   bl = 0;
#pragma unroll
    for (int i = 1; i < NL; ++i) {
      const float cc = s[i] + end_t[i];
      if (cc > bv) { bv = cc; bl = i; }
    }
    __syncthreads();

    // backtrace: chunked map composition over packed backpointer words.
    // lane tid owns t = 8*tid+1 .. 8*tid+8 -> exactly word-block tb = tid.
    uint32_t wv_[NL];
#pragma unroll
    for (int x = 0; x < NL; ++x) wv_[x] = bpw[tid * NL + x];
    uint64_t C = 0x876543210ULL;
#pragma unroll
    for (int k = 1; k <= 8; ++k) {
      const int t = 8 * tid + k;
      uint64_t nc = 0;
#pragma unroll
      for (int x = 0; x < 9; ++x) {
        const int g = (int)((wv_[x] >> (4 * (k - 1))) & 15u);
        nc |= ((C >> (4 * g)) & 15ULL) << (4 * x);
      }
      C = (t < len) ? nc : C;
    }
    const uint32_t Clo = (uint32_t)C, Chi = (uint32_t)(C >> 32);
    uint32_t cur = (uint32_t)bl;
    int bnd = 0;
#pragma unroll
    for (int c = 63; c >= 0; --c) {
      bnd = (tid == c) ? (int)cur : bnd;
      const uint32_t lo = (uint32_t)__builtin_amdgcn_readlane((int)Clo, c);
      const uint32_t hi = (uint32_t)__builtin_amdgcn_readlane((int)Chi, c);
      const uint64_t cc = ((uint64_t)hi << 32) | lo;
      cur = (uint32_t)((cc >> (4 * cur)) & 15u);
    }
    int tag = bnd;
#pragma unroll
    for (int k = 8; k >= 1; --k) {
      const int t = 8 * tid + k;
      const int tt = (t < 512) ? t : 511;
      const int blk2 = (tt - 1) >> 3;            // word block holding step tt
      const int kk   = tt - 8 * blk2;            // 1..8 within block
      const uint32_t bw = bpw[blk2 * NL + tag];  // dynamic LDS read (off-path)
      const int nt = (int)((bw >> (4 * (kk - 1))) & 15u);
      tag = (t < len) ? nt : tag;
      tags_s[t - 1] = (unsigned char)tag;
    }
    __syncthreads();
    for (int i = tid; i < EMN; i += 64) {
      const int t = i / NL;
      const int l = i - t * NL;
      out[1 + (size_t)b * EMN + i] =
          (t < len && l == (int)tags_s[t]) ? 1.0f : 0.0f;
    }

  } else if (blk < 128) {
    // ================= numerator =================
    const int b   = blk - 64;
    const int len = lens[b];
    const float* emb = logits + (size_t)b * EMN;
    for (int t = tid; t < SS; t += 64) {
      const int v = labels[b * SS + t];
      lab[t] = (unsigned char)((v == -100) ? 0 : v);
    }
    __syncthreads();
    float contrib = 0.0f;
    for (int t = tid; t < SS; t += 64) {
      if (t >= 1 && t < len)
        contrib += emb[t * NL + lab[t]] + trans[lab[t - 1] * NL + lab[t]];
    }
#pragma unroll
    for (int off = 32; off >= 1; off >>= 1)
      contrib += __shfl_xor(contrib, off, 64);
    if (tid == 0) {
      const int l0 = lab[0];
      num_den[b] = start_t[l0] + emb[l0] + contrib + end_t[lab[len - 1]];
    }

  } else {
    // ================= lognorm segment scan, 3 chains per wave =================
    const int id   = blk - 128;        // 0..1535
    const int pair = id / 3;           // (b, sg)
    const int wv   = id - pair * 3;    // which e-triple
    const int b    = pair >> 3;
    const int sg   = pair & 7;
    const int e0   = 3 * wv;           // chains e0, e0+1, e0+2
    const int len  = lens[b];
    const float* emb = logits + (size_t)b * EMN;
    float tc[NL];
#pragma unroll
    for (int i = 0; i < NL; ++i) tc[i] = trans[i * NL + j];
    float s0[NL], s1[NL], s2[NL];
#pragma unroll
    for (int i = 0; i < NL; ++i) {
      s0[i] = (i == e0)     ? 0.0f : NEG;
      s1[i] = (i == e0 + 1) ? 0.0f : NEG;
      s2[i] = (i == e0 + 2) ? 0.0f : NEG;
    }
    float my0 = (j == e0)     ? 0.0f : NEG;
    float my1 = (j == e0 + 1) ? 0.0f : NEG;
    float my2 = (j == e0 + 2) ? 0.0f : NEG;
    const int tbeg  = 64 * sg + 1;
    const int tlast = (64 * sg + 64 < 511) ? 64 * sg + 64 : 511;
    float eA = emb[tbeg * NL + j],       eB = emb[(tbeg + 1) * NL + j];
    float eC = emb[(tbeg + 2) * NL + j], eD = emb[(tbeg + 3) * NL + j];
    for (int t = tbeg; t <= tlast; ++t) {
      if (t >= len) break;             // prefix mask: rest are identity steps
      float c0[NL], c1[NL], c2[NL];
#pragma unroll
      for (int i = 0; i < NL; ++i) {
        c0[i] = s0[i] + tc[i];
        c1[i] = s1[i] + tc[i];
        c2[i] = s2[i] + tc[i];
      }
      // max via depth-2 max3 (exact); exp-sum order untouched (bit-identical)
      const float m0 = max9f(c0);
      const float m1 = max9f(c1);
      const float m2 = max9f(c2);
      float u0 = 0.0f, u1 = 0.0f, u2 = 0.0f;
#pragma unroll
      for (int i = 0; i < NL; ++i) {
        u0 += __expf(c0[i] - m0);
        u1 += __expf(c1[i] - m1);
        u2 += __expf(c2[i] - m2);
      }
      my0 = m0 + __logf(u0) + eA;
      my1 = m1 + __logf(u1) + eA;
      my2 = m2 + __logf(u2) + eA;
#pragma unroll
      for (int i = 0; i < NL; ++i) {
        s0[i] = readlane_f(my0, i);
        s1[i] = readlane_f(my1, i);
        s2[i] = readlane_f(my2, i);
      }
      eA = eB; eB = eC; eC = eD;
      eD = emb[(t + 4) * NL + j];
    }
    if (tid < NL) {
      float* M = segmat + (size_t)(b * NSEG + sg) * 81;
      M[(e0    ) * NL + tid] = my0;
      M[(e0 + 1) * NL + tid] = my1;
      M[(e0 + 2) * NL + tid] = my2;
    }
  }
}

// ---------------------------------------------------------------------------
// Kernel 3: combine + loss — per batch, chain the 8 segment matrices, get
// den = logsumexp(v + end_t), then atomically accumulate (den-num)/64.
// ---------------------------------------------------------------------------
__global__ __launch_bounds__(64) void combine_kernel(
    const float* __restrict__ logits, const float* __restrict__ segmat,
    const float* __restrict__ start_t, const float* __restrict__ end_t,
    const float* __restrict__ num_den, float* __restrict__ out) {
  const int b   = blockIdx.x;
  const int tid = threadIdx.x;
  const int j   = (tid < NL) ? tid : NL - 1;
  float s[NL];
#pragma unroll
  for (int i = 0; i < NL; ++i) s[i] = start_t[i] + logits[(size_t)b * EMN + i];
  float mcur[NL], mnxt[NL];
  {
    const float* M = segmat + (size_t)(b * NSEG) * 81;
#pragma unroll
    for (int i = 0; i < NL; ++i) mcur[i] = M[i * NL + j];
  }
  for (int sg = 0; sg < NSEG; ++sg) {
    if (sg + 1 < NSEG) {
      const float* M = segmat + (size_t)(b * NSEG + sg + 1) * 81;
#pragma unroll
      for (int i = 0; i < NL; ++i) mnxt[i] = M[i * NL + j];
    }
    float c[NL];
#pragma unroll
    for (int i = 0; i < NL; ++i) c[i] = s[i] + mcur[i];
    const float m = max9f(c);
    float sum = 0.0f;
#pragma unroll
    for (int i = 0; i < NL; ++i) sum += __expf(c[i] - m);
    const float nxt = m + __logf(sum);
#pragma unroll
    for (int i = 0; i < NL; ++i) s[i] = readlane_f(nxt, i);
#pragma unroll
    for (int i = 0; i < NL; ++i) mcur[i] = mnxt[i];
  }
  float c[NL];
#pragma unroll
  for (int i = 0; i < NL; ++i) c[i] = s[i] + end_t[i];
  const float m = max9f(c);
  float sum = 0.0f;
#pragma unroll
  for (int i = 0; i < NL; ++i) sum += __expf(c[i] - m);
  if (tid == 0) {
    const float den = m + __logf(sum);
    atomicAdd(out, (den - num_den[b]) * (1.0f / 64.0f));
  }
}

extern "C" void kernel_launch(void* const* d_in, const int* in_sizes, int n_in,
                              void* d_out, int out_size, void* d_ws, size_t ws_size,
                              hipStream_t stream) {
  const float* hidden  = (const float*)d_in[0];
  const int*   mask    = (const int*)d_in[1];
  const int*   labels  = (const int*)d_in[2];
  const float* W       = (const float*)d_in[3];
  const float* bias    = (const float*)d_in[4];
  const float* start_t = (const float*)d_in[5];
  const float* end_t   = (const float*)d_in[6];
  const float* trans   = (const float*)d_in[7];
  float* out = (float*)d_out;

  float* logits  = (float*)d_ws;                      // 294912 floats
  float* segmat  = logits + (size_t)NROWS * NL;       // 64*8*81 floats
  float* num_den = segmat + (size_t)BB * NSEG * 81;   // 64 floats (num)
  int*   lens    = (int*)(num_den + 128);             // 64 ints

  logits_kernel<<<2048, 256, 0, stream>>>(hidden, W, bias, mask, logits, lens, out);
  scan_kernel<<<1664, 64, 0, stream>>>(logits, labels, start_t, end_t, trans,
                                       out, num_den, lens, segmat);
  combine_kernel<<<64, 64, 0, stream>>>(logits, segmat, start_t, end_t,
                                        num_den, out);
}